// Round 1
// baseline (314.483 us; speedup 1.0000x reference)
//
#include <hip/hip_runtime.h>
#include <cstdint>
#include <cstddef>

// Problem constants (match reference)
#define Bn 4
#define Nn 2048
#define Dn 128
#define OUTn 64
#define Sn 8          // 4 batches x {fwd, rev}
#define MAXDEG 256    // binomial(2048, 1/32): mean 64, P(deg>=256) ~ 0
#define NITER 3

// ---------------------------------------------------------------------------
// deg[i] = 0 for i < Sn*Nn
__global__ void zero_deg(int* __restrict__ deg) {
    int i = blockIdx.x * blockDim.x + threadIdx.x;
    deg[i] = 0;
}

// ---------------------------------------------------------------------------
// One wave per forward row (b,i). Coalesced scan of CFG row:
//  - forward adjacency via ballot compaction (deterministic, sorted by j)
//  - reverse adjacency via atomicAdd fill (sorted afterwards by sort_rev)
__global__ void build_adj(const float* __restrict__ cfg,
                          int* __restrict__ adj, int* __restrict__ deg) {
    int row  = blockIdx.x * 4 + (threadIdx.x >> 6);   // [0, Bn*Nn)
    int lane = threadIdx.x & 63;
    int b = row >> 11;            // /Nn
    int i = row & (Nn - 1);
    const float* crow = cfg + ((size_t)(b * Nn + i)) * Nn;
    int cnt = 0;
    for (int j0 = 0; j0 < Nn; j0 += 64) {
        int j = j0 + lane;
        bool e = (crow[j] != 0.0f);
        unsigned long long m = __ballot(e);
        int pre = __popcll(m & ((1ull << lane) - 1ull));
        if (e) {
            int posf = cnt + pre;
            if (posf < MAXDEG) adj[(size_t)row * MAXDEG + posf] = j;
            int r2 = (4 + b) * Nn + j;                // reverse row (slot 4+b)
            int pos = atomicAdd(&deg[r2], 1);
            if (pos < MAXDEG) adj[(size_t)r2 * MAXDEG + pos] = i;
        }
        cnt += __popcll(m);
    }
    if (lane == 0) deg[row] = (cnt < MAXDEG ? cnt : MAXDEG);
}

// ---------------------------------------------------------------------------
// Canonicalize reverse adjacency lists (atomic fill order is nondeterministic).
// Even-odd transposition sort in LDS; d passes suffice for d elements.
__global__ void sort_rev(int* __restrict__ adj, const int* __restrict__ deg) {
    int r = Bn * Nn + blockIdx.x;                     // reverse rows only
    int d = deg[r]; if (d > MAXDEG) d = MAXDEG;
    if (d <= 1) return;
    __shared__ int a[MAXDEG];
    int* base = adj + (size_t)r * MAXDEG;
    for (int k = threadIdx.x; k < d; k += blockDim.x) a[k] = base[k];
    __syncthreads();
    for (int pass = 0; pass < d; ++pass) {
        int idx = (pass & 1) + 2 * threadIdx.x;
        if (idx + 1 < d) {
            int x0 = a[idx], x1 = a[idx + 1];
            if (x0 > x1) { a[idx] = x1; a[idx + 1] = x0; }
        }
        __syncthreads();
    }
    for (int k = threadIdx.x; k < d; k += blockDim.x) base[k] = a[k];
}

// ---------------------------------------------------------------------------
// x[s] = relu(INPUT[b]) for s = b and s = b+4
__global__ void init_x(const float* __restrict__ in, float* __restrict__ x) {
    int t = blockIdx.x * blockDim.x + threadIdx.x;    // [0, Bn*Nn*Dn)
    float v = in[t];
    v = v > 0.0f ? v : 0.0f;
    x[t] = v;
    x[(size_t)Bn * Nn * Dn + t] = v;
}

// ---------------------------------------------------------------------------
// xw = x @ W for all Sn*Nn rows. 8 rows per 128-thread block; x-row loads are
// wave-uniform (scalar path), W loads coalesced + L1/L2 resident.
__global__ void gemm_xw(const float* __restrict__ x, const float* __restrict__ W,
                        float* __restrict__ xw) {
    int c = threadIdx.x;                              // column 0..127
    size_t rbase = (size_t)blockIdx.x * 8 * Dn;
    const float* x0 = x + rbase;
    float a0 = 0.f, a1 = 0.f, a2 = 0.f, a3 = 0.f;
    float a4 = 0.f, a5 = 0.f, a6 = 0.f, a7 = 0.f;
    #pragma unroll 4
    for (int k = 0; k < Dn; ++k) {
        float w = W[k * Dn + c];
        a0 = fmaf(x0[0 * Dn + k], w, a0);
        a1 = fmaf(x0[1 * Dn + k], w, a1);
        a2 = fmaf(x0[2 * Dn + k], w, a2);
        a3 = fmaf(x0[3 * Dn + k], w, a3);
        a4 = fmaf(x0[4 * Dn + k], w, a4);
        a5 = fmaf(x0[5 * Dn + k], w, a5);
        a6 = fmaf(x0[6 * Dn + k], w, a6);
        a7 = fmaf(x0[7 * Dn + k], w, a7);
    }
    xw[rbase + 0 * Dn + c] = a0;
    xw[rbase + 1 * Dn + c] = a1;
    xw[rbase + 2 * Dn + c] = a2;
    xw[rbase + 3 * Dn + c] = a3;
    xw[rbase + 4 * Dn + c] = a4;
    xw[rbase + 5 * Dn + c] = a5;
    xw[rbase + 6 * Dn + c] = a6;
    xw[rbase + 7 * Dn + c] = a7;
}

// ---------------------------------------------------------------------------
// ah1[r] = x[r]·w1 + b1 ; ah2[r] = x[r]·w2 + b2. One wave per row.
__global__ void compute_ah(const float* __restrict__ x,
                           const float* __restrict__ w1, const float* __restrict__ b1,
                           const float* __restrict__ w2, const float* __restrict__ b2,
                           float* __restrict__ ah1, float* __restrict__ ah2) {
    int r = blockIdx.x * 4 + (threadIdx.x >> 6);
    int lane = threadIdx.x & 63;
    const float* xr = x + (size_t)r * Dn;
    float x0 = xr[lane], x1 = xr[64 + lane];
    float d1 = x0 * w1[lane] + x1 * w1[64 + lane];
    float d2 = x0 * w2[lane] + x1 * w2[64 + lane];
    #pragma unroll
    for (int o = 32; o > 0; o >>= 1) {
        d1 += __shfl_xor(d1, o);
        d2 += __shfl_xor(d2, o);
    }
    if (lane == 0) { ah1[r] = d1 + b1[0]; ah2[r] = d2 + b2[0]; }
}

// ---------------------------------------------------------------------------
// Fused: masked softmax over neighbor list + sparse aggregate of xw + residual
// + ELU, updating x in place (row-private). Block = 128 threads (thread = d).
// blockIdx swizzle: slot = blockIdx&7 so each XCD's L2 tends to hold one
// slot's 1MB xw table.
__global__ void attn_agg(float* __restrict__ x, const float* __restrict__ xw,
                         const int* __restrict__ adj, const int* __restrict__ deg,
                         const float* __restrict__ ah1, const float* __restrict__ ah2) {
    int s = blockIdx.x & 7;
    int i = blockIdx.x >> 3;
    int r = s * Nn + i;
    int tid = threadIdx.x;

    __shared__ float p[MAXDEG];
    __shared__ int   nb[MAXDEG];
    __shared__ float zsh;

    int d = deg[r]; if (d > MAXDEG) d = MAXDEG;

    if (tid < 64 && d > 0) {
        float a1 = ah1[r];
        const int* al = adj + (size_t)r * MAXDEG;
        const float* ah2s = ah2 + (size_t)s * Nn;
        float v[4];
        float m = -INFINITY;
        #pragma unroll
        for (int t = 0; t < 4; ++t) {
            int k = tid + t * 64;
            if (k < d) {
                int j = al[k];
                nb[k] = j;
                float e = a1 + ah2s[j];
                e = e > 0.f ? e : 0.2f * e;   // leaky_relu(0.2)
                v[t] = e;
                m = fmaxf(m, e);
            } else v[t] = -INFINITY;
        }
        #pragma unroll
        for (int o = 32; o > 0; o >>= 1) m = fmaxf(m, __shfl_xor(m, o));
        float sum = 0.f;
        #pragma unroll
        for (int t = 0; t < 4; ++t) {
            int k = tid + t * 64;
            if (k < d) {
                float ex = __expf(v[t] - m);
                p[k] = ex;
                sum += ex;
            }
        }
        #pragma unroll
        for (int o = 32; o > 0; o >>= 1) sum += __shfl_xor(sum, o);
        if (tid == 0) zsh = sum;
    }
    __syncthreads();

    const float* xwS = xw + (size_t)s * Nn * Dn;
    float acc = 0.f;
    int k = 0;
    for (; k + 3 < d; k += 4) {
        float p0 = p[k], p1 = p[k+1], p2 = p[k+2], p3 = p[k+3];
        int j0 = nb[k], j1 = nb[k+1], j2 = nb[k+2], j3 = nb[k+3];
        acc += p0 * xwS[(size_t)j0 * Dn + tid];
        acc += p1 * xwS[(size_t)j1 * Dn + tid];
        acc += p2 * xwS[(size_t)j2 * Dn + tid];
        acc += p3 * xwS[(size_t)j3 * Dn + tid];
    }
    for (; k < d; ++k) acc += p[k] * xwS[(size_t)nb[k] * Dn + tid];

    size_t xi = (size_t)r * Dn + tid;
    float v0 = x[xi];
    float res;
    if (d > 0) {
        float t = v0 + acc / zsh;
        res = t > 0.f ? t : (expf(t) - 1.f);   // elu
    } else {
        res = v0 > 0.f ? v0 : (expf(v0) - 1.f);
    }
    x[xi] = res;
}

// ---------------------------------------------------------------------------
// Stage-1 reduction over rows: 32 chunks of 64 rows per batch, fwd+rev fused.
__global__ void reduce_partial(const float* __restrict__ x, float* __restrict__ part) {
    int b = blockIdx.x >> 5;
    int c = blockIdx.x & 31;
    int tid = threadIdx.x;                     // 0..127 = d
    const float* xf = x + ((size_t)(b * Nn) + c * 64) * Dn;
    const float* xr = x + ((size_t)((4 + b) * Nn) + c * 64) * Dn;
    float sv = 0.f;
    for (int i = 0; i < 64; ++i)
        sv += xf[(size_t)i * Dn + tid] + xr[(size_t)i * Dn + tid];
    part[(size_t)blockIdx.x * Dn + tid] = sv;
}

// ---------------------------------------------------------------------------
// Stage-2: mid[b] = sum of partials; out[b] = mid @ Wout + bout
__global__ void final_out(const float* __restrict__ part,
                          const float* __restrict__ Wout, const float* __restrict__ bout,
                          float* __restrict__ out) {
    int b = blockIdx.x;
    int tid = threadIdx.x;                     // 128 threads
    __shared__ float mid[Dn];
    float sv = 0.f;
    for (int c = 0; c < 32; ++c) sv += part[(size_t)(b * 32 + c) * Dn + tid];
    mid[tid] = sv;
    __syncthreads();
    if (tid < OUTn) {
        float o = bout[tid];
        #pragma unroll 4
        for (int k = 0; k < Dn; ++k) o = fmaf(mid[k], Wout[k * OUTn + tid], o);
        out[b * OUTn + tid] = o;
    }
}

// ---------------------------------------------------------------------------
extern "C" void kernel_launch(void* const* d_in, const int* in_sizes, int n_in,
                              void* d_out, int out_size, void* d_ws, size_t ws_size,
                              hipStream_t stream) {
    const float* INPUT = (const float*)d_in[0];
    const float* CFG   = (const float*)d_in[1];
    // d_in[2] = LFG, unused by the forward pass
    const float* w1    = (const float*)d_in[3];
    const float* b1    = (const float*)d_in[4];
    const float* w2    = (const float*)d_in[5];
    const float* b2    = (const float*)d_in[6];
    const float* Wm    = (const float*)d_in[7];
    const float* Wout  = (const float*)d_in[8];
    const float* bout  = (const float*)d_in[9];
    float* out = (float*)d_out;

    // workspace layout (~32.3 MB)
    float* x   = (float*)d_ws;                          // Sn*Nn*Dn   (8 MB)
    float* xw  = x + (size_t)Sn * Nn * Dn;              // Sn*Nn*Dn   (8 MB)
    int*   adj = (int*)(xw + (size_t)Sn * Nn * Dn);     // Sn*Nn*MAXDEG (16 MB)
    int*   deg = adj + (size_t)Sn * Nn * MAXDEG;        // Sn*Nn      (64 KB)
    float* ah1 = (float*)(deg + Sn * Nn);               // Sn*Nn      (64 KB)
    float* ah2 = ah1 + Sn * Nn;                         // Sn*Nn      (64 KB)
    float* part = ah2 + Sn * Nn;                        // Bn*32*Dn   (64 KB)

    zero_deg <<<(Sn * Nn) / 256, 256, 0, stream>>>(deg);
    build_adj<<<(Bn * Nn) / 4, 256, 0, stream>>>(CFG, adj, deg);
    sort_rev <<<Bn * Nn, 128, 0, stream>>>(adj, deg);
    init_x   <<<(Bn * Nn * Dn) / 256, 256, 0, stream>>>(INPUT, x);

    for (int it = 0; it < NITER; ++it) {
        gemm_xw   <<<(Sn * Nn) / 8, 128, 0, stream>>>(x, Wm, xw);
        compute_ah<<<(Sn * Nn) / 4, 256, 0, stream>>>(x, w1, b1, w2, b2, ah1, ah2);
        attn_agg  <<<Sn * Nn, 128, 0, stream>>>(x, xw, adj, deg, ah1, ah2);
    }

    reduce_partial<<<Bn * 32, 128, 0, stream>>>(x, part);
    final_out     <<<Bn, 128, 0, stream>>>(part, Wout, bout, out);
}

// Round 2
// 274.150 us; speedup vs baseline: 1.1471x; 1.1471x over previous
//
#include <hip/hip_runtime.h>
#include <cstdint>
#include <cstddef>

// Problem constants (match reference)
#define Bn 4
#define Nn 2048
#define Dn 128
#define OUTn 64
#define Sn 8          // 4 batches x {fwd, rev}
#define MAXDEG 128    // binomial(2048, 1/32): mean 64, sd 7.9; max over 16K rows ~99
#define NITER 3

// ---------------------------------------------------------------------------
// deposit low 16 bits of x at bit positions 0,4,8,...,60
__device__ __forceinline__ unsigned long long spread4(unsigned long long x) {
    x &= 0xFFFFull;
    x = (x | (x << 24)) & 0x000000FF000000FFull;
    x = (x | (x << 12)) & 0x000F000F000F000Full;
    x = (x | (x << 6))  & 0x0303030303030303ull;
    x = (x | (x << 3))  & 0x1111111111111111ull;
    return x;
}

// ---------------------------------------------------------------------------
// One wave per forward row (b,i). float4 loads (16B/lane => 256 cols/iter).
// Produces: forward adjacency (sorted, deterministic), degree, and a bitmask
// of CFG (u64 per 64 cols) for the reverse pass.
__global__ void fwd_and_bits(const float4* __restrict__ cfg4,
                             unsigned long long* __restrict__ bits,
                             int* __restrict__ adj, int* __restrict__ deg) {
    int row  = blockIdx.x * 4 + (threadIdx.x >> 6);   // [0, Bn*Nn)
    int lane = threadIdx.x & 63;
    const float4* crow = cfg4 + (size_t)row * (Nn / 4);
    int* dst = adj + (size_t)row * MAXDEG;
    unsigned long long* brow = bits + (size_t)row * (Nn / 64);
    int cnt = 0;
    for (int j0 = 0; j0 < Nn; j0 += 256) {
        float4 v = crow[(j0 >> 2) + lane];
        int nib = (v.x != 0.f) | ((v.y != 0.f) << 1) |
                  ((v.z != 0.f) << 2) | ((v.w != 0.f) << 3);
        unsigned long long m0 = __ballot(nib & 1);
        unsigned long long m1 = __ballot(nib & 2);
        unsigned long long m2 = __ballot(nib & 4);
        unsigned long long m3 = __ballot(nib & 8);
        // exclusive prefix (in ascending-column order) for this lane
        unsigned long long below = (lane == 63) ? ~0ull >> 1 : ((1ull << lane) - 1ull);
        below = (1ull << lane) - 1ull;   // lane<64 => safe (lane=63 gives low 63 bits)
        int off = __popcll(m0 & below) + __popcll(m1 & below) +
                  __popcll(m2 & below) + __popcll(m3 & below);
        int total = __popcll(m0) + __popcll(m1) + __popcll(m2) + __popcll(m3);
        int base = cnt + off;
        int col = j0 + 4 * lane;
        if (nib & 1) { if (base < MAXDEG) dst[base] = col;     base++; }
        if (nib & 2) { if (base < MAXDEG) dst[base] = col + 1; base++; }
        if (nib & 4) { if (base < MAXDEG) dst[base] = col + 2; base++; }
        if (nib & 8) { if (base < MAXDEG) dst[base] = col + 3; base++; }
        // assemble the 4 bitmask words (cols j0+64w .. j0+64w+63), lanes 0..3
        if (lane < 4) {
            int sh = lane << 4;
            unsigned long long w = spread4(m0 >> sh) | (spread4(m1 >> sh) << 1) |
                                   (spread4(m2 >> sh) << 2) | (spread4(m3 >> sh) << 3);
            brow[(j0 >> 6) + lane] = w;
        }
        cnt += total;
    }
    if (lane == 0) deg[row] = (cnt < MAXDEG ? cnt : MAXDEG);
}

// ---------------------------------------------------------------------------
// One wave per reverse row (b,j): scan column j of the bitmask (L2-resident),
// ballot-compact ascending i. Deterministic and sorted — no atomics, no sort.
__global__ void rev_adj(const unsigned long long* __restrict__ bits,
                        int* __restrict__ adj, int* __restrict__ deg) {
    int r    = blockIdx.x * 4 + (threadIdx.x >> 6);   // [0, Bn*Nn)
    int lane = threadIdx.x & 63;
    int b = r >> 11;
    int j = r & (Nn - 1);
    const unsigned long long* base = bits + (size_t)b * Nn * (Nn / 64) + (j >> 6);
    int bit = j & 63;
    int out_r = (Bn + b) * Nn + j;
    int* dst = adj + (size_t)out_r * MAXDEG;
    int cnt = 0;
    for (int i0 = 0; i0 < Nn; i0 += 64) {
        unsigned long long word = base[(size_t)(i0 + lane) * (Nn / 64)];
        bool e = (word >> bit) & 1;
        unsigned long long m = __ballot(e);
        if (e) {
            int pos = cnt + __popcll(m & ((1ull << lane) - 1ull));
            if (pos < MAXDEG) dst[pos] = i0 + lane;
        }
        cnt += __popcll(m);
    }
    if (lane == 0) deg[out_r] = (cnt < MAXDEG ? cnt : MAXDEG);
}

// ---------------------------------------------------------------------------
// x[s] = relu(INPUT[b]) for s = b and s = b+4
__global__ void init_x(const float* __restrict__ in, float* __restrict__ x) {
    int t = blockIdx.x * blockDim.x + threadIdx.x;    // [0, Bn*Nn*Dn)
    float v = in[t];
    v = v > 0.0f ? v : 0.0f;
    x[t] = v;
    x[(size_t)Bn * Nn * Dn + t] = v;
}

// ---------------------------------------------------------------------------
// xw = x @ W for all Sn*Nn rows. 8 rows per 128-thread block; x-row loads are
// wave-uniform (scalar path), W loads coalesced + L1/L2 resident.
__global__ void gemm_xw(const float* __restrict__ x, const float* __restrict__ W,
                        float* __restrict__ xw) {
    int c = threadIdx.x;                              // column 0..127
    size_t rbase = (size_t)blockIdx.x * 8 * Dn;
    const float* x0 = x + rbase;
    float a0 = 0.f, a1 = 0.f, a2 = 0.f, a3 = 0.f;
    float a4 = 0.f, a5 = 0.f, a6 = 0.f, a7 = 0.f;
    #pragma unroll 4
    for (int k = 0; k < Dn; ++k) {
        float w = W[k * Dn + c];
        a0 = fmaf(x0[0 * Dn + k], w, a0);
        a1 = fmaf(x0[1 * Dn + k], w, a1);
        a2 = fmaf(x0[2 * Dn + k], w, a2);
        a3 = fmaf(x0[3 * Dn + k], w, a3);
        a4 = fmaf(x0[4 * Dn + k], w, a4);
        a5 = fmaf(x0[5 * Dn + k], w, a5);
        a6 = fmaf(x0[6 * Dn + k], w, a6);
        a7 = fmaf(x0[7 * Dn + k], w, a7);
    }
    xw[rbase + 0 * Dn + c] = a0;
    xw[rbase + 1 * Dn + c] = a1;
    xw[rbase + 2 * Dn + c] = a2;
    xw[rbase + 3 * Dn + c] = a3;
    xw[rbase + 4 * Dn + c] = a4;
    xw[rbase + 5 * Dn + c] = a5;
    xw[rbase + 6 * Dn + c] = a6;
    xw[rbase + 7 * Dn + c] = a7;
}

// ---------------------------------------------------------------------------
// ah1[r] = x[r]·w1 + b1 ; ah2[r] = x[r]·w2 + b2. One wave per row.
__global__ void compute_ah(const float* __restrict__ x,
                           const float* __restrict__ w1, const float* __restrict__ b1,
                           const float* __restrict__ w2, const float* __restrict__ b2,
                           float* __restrict__ ah1, float* __restrict__ ah2) {
    int r = blockIdx.x * 4 + (threadIdx.x >> 6);
    int lane = threadIdx.x & 63;
    const float* xr = x + (size_t)r * Dn;
    float x0 = xr[lane], x1 = xr[64 + lane];
    float d1 = x0 * w1[lane] + x1 * w1[64 + lane];
    float d2 = x0 * w2[lane] + x1 * w2[64 + lane];
    #pragma unroll
    for (int o = 32; o > 0; o >>= 1) {
        d1 += __shfl_xor(d1, o);
        d2 += __shfl_xor(d2, o);
    }
    if (lane == 0) { ah1[r] = d1 + b1[0]; ah2[r] = d2 + b2[0]; }
}

// ---------------------------------------------------------------------------
// Fused: masked softmax over neighbor list + sparse aggregate of xw + residual
// + ELU, updating x in place (row-private). Block = 128 threads (thread = d).
// blockIdx swizzle: slot = blockIdx&7 so each XCD's L2 tends to hold one
// slot's 1MB xw table.
__global__ void attn_agg(float* __restrict__ x, const float* __restrict__ xw,
                         const int* __restrict__ adj, const int* __restrict__ deg,
                         const float* __restrict__ ah1, const float* __restrict__ ah2) {
    int s = blockIdx.x & 7;
    int i = blockIdx.x >> 3;
    int r = s * Nn + i;
    int tid = threadIdx.x;

    __shared__ float p[MAXDEG];
    __shared__ int   nb[MAXDEG];
    __shared__ float zsh;

    int d = deg[r]; if (d > MAXDEG) d = MAXDEG;

    if (tid < 64 && d > 0) {
        float a1 = ah1[r];
        const int* al = adj + (size_t)r * MAXDEG;
        const float* ah2s = ah2 + (size_t)s * Nn;
        float v[2];
        float m = -INFINITY;
        #pragma unroll
        for (int t = 0; t < 2; ++t) {
            int k = tid + t * 64;
            if (k < d) {
                int j = al[k];
                nb[k] = j;
                float e = a1 + ah2s[j];
                e = e > 0.f ? e : 0.2f * e;   // leaky_relu(0.2)
                v[t] = e;
                m = fmaxf(m, e);
            } else v[t] = -INFINITY;
        }
        #pragma unroll
        for (int o = 32; o > 0; o >>= 1) m = fmaxf(m, __shfl_xor(m, o));
        float sum = 0.f;
        #pragma unroll
        for (int t = 0; t < 2; ++t) {
            int k = tid + t * 64;
            if (k < d) {
                float ex = __expf(v[t] - m);
                p[k] = ex;
                sum += ex;
            }
        }
        #pragma unroll
        for (int o = 32; o > 0; o >>= 1) sum += __shfl_xor(sum, o);
        if (tid == 0) zsh = sum;
    }
    __syncthreads();

    const float* xwS = xw + (size_t)s * Nn * Dn;
    float acc = 0.f;
    int k = 0;
    for (; k + 3 < d; k += 4) {
        float p0 = p[k], p1 = p[k+1], p2 = p[k+2], p3 = p[k+3];
        int j0 = nb[k], j1 = nb[k+1], j2 = nb[k+2], j3 = nb[k+3];
        acc += p0 * xwS[(size_t)j0 * Dn + tid];
        acc += p1 * xwS[(size_t)j1 * Dn + tid];
        acc += p2 * xwS[(size_t)j2 * Dn + tid];
        acc += p3 * xwS[(size_t)j3 * Dn + tid];
    }
    for (; k < d; ++k) acc += p[k] * xwS[(size_t)nb[k] * Dn + tid];

    size_t xi = (size_t)r * Dn + tid;
    float v0 = x[xi];
    float res;
    if (d > 0) {
        float t = v0 + acc / zsh;
        res = t > 0.f ? t : (expf(t) - 1.f);   // elu
    } else {
        res = v0 > 0.f ? v0 : (expf(v0) - 1.f);
    }
    x[xi] = res;
}

// ---------------------------------------------------------------------------
// Stage-1 reduction over rows: 32 chunks of 64 rows per batch, fwd+rev fused.
__global__ void reduce_partial(const float* __restrict__ x, float* __restrict__ part) {
    int b = blockIdx.x >> 5;
    int c = blockIdx.x & 31;
    int tid = threadIdx.x;                     // 0..127 = d
    const float* xf = x + ((size_t)(b * Nn) + c * 64) * Dn;
    const float* xr = x + ((size_t)((4 + b) * Nn) + c * 64) * Dn;
    float sv = 0.f;
    for (int i = 0; i < 64; ++i)
        sv += xf[(size_t)i * Dn + tid] + xr[(size_t)i * Dn + tid];
    part[(size_t)blockIdx.x * Dn + tid] = sv;
}

// ---------------------------------------------------------------------------
// Stage-2: mid[b] = sum of partials; out[b] = mid @ Wout + bout
__global__ void final_out(const float* __restrict__ part,
                          const float* __restrict__ Wout, const float* __restrict__ bout,
                          float* __restrict__ out) {
    int b = blockIdx.x;
    int tid = threadIdx.x;                     // 128 threads
    __shared__ float mid[Dn];
    float sv = 0.f;
    for (int c = 0; c < 32; ++c) sv += part[(size_t)(b * 32 + c) * Dn + tid];
    mid[tid] = sv;
    __syncthreads();
    if (tid < OUTn) {
        float o = bout[tid];
        #pragma unroll 4
        for (int k = 0; k < Dn; ++k) o = fmaf(mid[k], Wout[k * OUTn + tid], o);
        out[b * OUTn + tid] = o;
    }
}

// ---------------------------------------------------------------------------
extern "C" void kernel_launch(void* const* d_in, const int* in_sizes, int n_in,
                              void* d_out, int out_size, void* d_ws, size_t ws_size,
                              hipStream_t stream) {
    const float* INPUT = (const float*)d_in[0];
    const float* CFG   = (const float*)d_in[1];
    // d_in[2] = LFG, unused by the forward pass
    const float* w1    = (const float*)d_in[3];
    const float* b1    = (const float*)d_in[4];
    const float* w2    = (const float*)d_in[5];
    const float* b2    = (const float*)d_in[6];
    const float* Wm    = (const float*)d_in[7];
    const float* Wout  = (const float*)d_in[8];
    const float* bout  = (const float*)d_in[9];
    float* out = (float*)d_out;

    // workspace layout (~26.4 MB)
    float* x   = (float*)d_ws;                          // Sn*Nn*Dn   (8 MB)
    float* xw  = x + (size_t)Sn * Nn * Dn;              // Sn*Nn*Dn   (8 MB)
    int*   adj = (int*)(xw + (size_t)Sn * Nn * Dn);     // Sn*Nn*MAXDEG (8 MB)
    int*   deg = adj + (size_t)Sn * Nn * MAXDEG;        // Sn*Nn      (64 KB)
    float* ah1 = (float*)(deg + Sn * Nn);               // Sn*Nn      (64 KB)
    float* ah2 = ah1 + Sn * Nn;                         // Sn*Nn      (64 KB)
    float* part = ah2 + Sn * Nn;                        // Bn*32*Dn   (64 KB)
    unsigned long long* bits = (unsigned long long*)(part + Bn * 32 * Dn); // 2 MB

    fwd_and_bits<<<(Bn * Nn) / 4, 256, 0, stream>>>((const float4*)CFG, bits, adj, deg);
    rev_adj     <<<(Bn * Nn) / 4, 256, 0, stream>>>(bits, adj, deg);
    init_x      <<<(Bn * Nn * Dn) / 256, 256, 0, stream>>>(INPUT, x);

    for (int it = 0; it < NITER; ++it) {
        gemm_xw   <<<(Sn * Nn) / 8, 128, 0, stream>>>(x, Wm, xw);
        compute_ah<<<(Sn * Nn) / 4, 256, 0, stream>>>(x, w1, b1, w2, b2, ah1, ah2);
        attn_agg  <<<Sn * Nn, 128, 0, stream>>>(x, xw, adj, deg, ah1, ah2);
    }

    reduce_partial<<<Bn * 32, 128, 0, stream>>>(x, part);
    final_out     <<<Bn, 128, 0, stream>>>(part, Wout, bout, out);
}

// Round 3
// 230.849 us; speedup vs baseline: 1.3623x; 1.1876x over previous
//
#include <hip/hip_runtime.h>
#include <cstdint>
#include <cstddef>

// Problem constants (match reference)
#define Bn 4
#define Nn 2048
#define Dn 128
#define OUTn 64
#define Sn 8          // 4 batches x {fwd, rev}
#define MAXDEG 128    // binomial(2048, 1/32): mean 64, sd 7.9; max over 16K rows ~99
#define NITER 3

// ---------------------------------------------------------------------------
// deposit low 16 bits of x at bit positions 0,4,8,...,60
__device__ __forceinline__ unsigned long long spread4(unsigned long long x) {
    x &= 0xFFFFull;
    x = (x | (x << 24)) & 0x000000FF000000FFull;
    x = (x | (x << 12)) & 0x000F000F000F000Full;
    x = (x | (x << 6))  & 0x0303030303030303ull;
    x = (x | (x << 3))  & 0x1111111111111111ull;
    return x;
}

// ---------------------------------------------------------------------------
// One wave per forward row (b,i). float4 loads (16B/lane => 256 cols/iter).
// Produces: forward adjacency (sorted, deterministic), degree, and a bitmask
// of CFG stored word-COLUMN-major: bits[b][jw][i] (jw = j/64, i = row).
// This makes the reverse pass read contiguous 2048-word planes.
__global__ void fwd_and_bits(const float4* __restrict__ cfg4,
                             unsigned long long* __restrict__ bits,
                             int* __restrict__ adj, int* __restrict__ deg) {
    int row  = blockIdx.x * 4 + (threadIdx.x >> 6);   // [0, Bn*Nn)
    int lane = threadIdx.x & 63;
    int b = row >> 11;
    int i = row & (Nn - 1);
    const float4* crow = cfg4 + (size_t)row * (Nn / 4);
    int* dst = adj + (size_t)row * MAXDEG;
    int cnt = 0;
    for (int j0 = 0; j0 < Nn; j0 += 256) {
        float4 v = crow[(j0 >> 2) + lane];
        int nib = (v.x != 0.f) | ((v.y != 0.f) << 1) |
                  ((v.z != 0.f) << 2) | ((v.w != 0.f) << 3);
        unsigned long long m0 = __ballot(nib & 1);
        unsigned long long m1 = __ballot(nib & 2);
        unsigned long long m2 = __ballot(nib & 4);
        unsigned long long m3 = __ballot(nib & 8);
        // exclusive prefix (ascending-column order) for this lane
        unsigned long long below = (1ull << lane) - 1ull;  // lane 63: low 63 bits
        int off = __popcll(m0 & below) + __popcll(m1 & below) +
                  __popcll(m2 & below) + __popcll(m3 & below);
        int total = __popcll(m0) + __popcll(m1) + __popcll(m2) + __popcll(m3);
        int base = cnt + off;
        int col = j0 + 4 * lane;
        if (nib & 1) { if (base < MAXDEG) dst[base] = col;     base++; }
        if (nib & 2) { if (base < MAXDEG) dst[base] = col + 1; base++; }
        if (nib & 4) { if (base < MAXDEG) dst[base] = col + 2; base++; }
        if (nib & 8) { if (base < MAXDEG) dst[base] = col + 3; base++; }
        // assemble the 4 bitmask words (cols j0+64w .. j0+64w+63), lanes 0..3
        if (lane < 4) {
            int sh = lane << 4;
            unsigned long long w = spread4(m0 >> sh) | (spread4(m1 >> sh) << 1) |
                                   (spread4(m2 >> sh) << 2) | (spread4(m3 >> sh) << 3);
            int jw = (j0 >> 6) + lane;
            bits[((size_t)(b * 32 + jw)) * Nn + i] = w;
        }
        cnt += total;
    }
    if (lane == 0) deg[row] = (cnt < MAXDEG ? cnt : MAXDEG);
}

// ---------------------------------------------------------------------------
// One wave per reverse row (b,j): read plane bits[b][j>>6][*] CONTIGUOUSLY
// (lane l -> word i0+lane, 512B per instruction; the 16KB plane is shared by
// 64 consecutive rows -> L1-resident). Ballot-compact ascending i.
// Deterministic and sorted — no atomics, no sort.
__global__ void rev_adj(const unsigned long long* __restrict__ bits,
                        int* __restrict__ adj, int* __restrict__ deg) {
    int r    = blockIdx.x * 4 + (threadIdx.x >> 6);   // [0, Bn*Nn)
    int lane = threadIdx.x & 63;
    int b = r >> 11;
    int j = r & (Nn - 1);
    const unsigned long long* col = bits + ((size_t)(b * 32 + (j >> 6))) * Nn;
    int bit = j & 63;
    int out_r = (Bn + b) * Nn + j;
    int* dst = adj + (size_t)out_r * MAXDEG;
    int cnt = 0;
    for (int i0 = 0; i0 < Nn; i0 += 64) {
        unsigned long long word = col[i0 + lane];
        bool e = (word >> bit) & 1;
        unsigned long long m = __ballot(e);
        if (e) {
            int pos = cnt + __popcll(m & ((1ull << lane) - 1ull));
            if (pos < MAXDEG) dst[pos] = i0 + lane;
        }
        cnt += __popcll(m);
    }
    if (lane == 0) deg[out_r] = (cnt < MAXDEG ? cnt : MAXDEG);
}

// ---------------------------------------------------------------------------
// x[s] = relu(INPUT[b]) for s = b and s = b+4
__global__ void init_x(const float* __restrict__ in, float* __restrict__ x) {
    int t = blockIdx.x * blockDim.x + threadIdx.x;    // [0, Bn*Nn*Dn)
    float v = in[t];
    v = v > 0.0f ? v : 0.0f;
    x[t] = v;
    x[(size_t)Bn * Nn * Dn + t] = v;
}

// ---------------------------------------------------------------------------
// Fused: xw = x @ W (8 rows per 128-thread block; x-row loads wave-uniform ->
// scalar path, W loads coalesced + cache resident) AND per-row attention
// scalars ah1/ah2 (shfl reduction over the feature dim).
__global__ void gemm_xw_ah(const float* __restrict__ x, const float* __restrict__ W,
                           float* __restrict__ xw,
                           const float* __restrict__ w1, const float* __restrict__ b1,
                           const float* __restrict__ w2, const float* __restrict__ b2,
                           float* __restrict__ ah1, float* __restrict__ ah2) {
    int c = threadIdx.x;                              // column 0..127
    int wv = c >> 6, lane = c & 63;
    size_t rbase = (size_t)blockIdx.x * 8 * Dn;
    const float* x0 = x + rbase;
    float a0 = 0.f, a1 = 0.f, a2 = 0.f, a3 = 0.f;
    float a4 = 0.f, a5 = 0.f, a6 = 0.f, a7 = 0.f;
    #pragma unroll 4
    for (int k = 0; k < Dn; ++k) {
        float w = W[k * Dn + c];
        a0 = fmaf(x0[0 * Dn + k], w, a0);
        a1 = fmaf(x0[1 * Dn + k], w, a1);
        a2 = fmaf(x0[2 * Dn + k], w, a2);
        a3 = fmaf(x0[3 * Dn + k], w, a3);
        a4 = fmaf(x0[4 * Dn + k], w, a4);
        a5 = fmaf(x0[5 * Dn + k], w, a5);
        a6 = fmaf(x0[6 * Dn + k], w, a6);
        a7 = fmaf(x0[7 * Dn + k], w, a7);
    }
    xw[rbase + 0 * Dn + c] = a0;
    xw[rbase + 1 * Dn + c] = a1;
    xw[rbase + 2 * Dn + c] = a2;
    xw[rbase + 3 * Dn + c] = a3;
    xw[rbase + 4 * Dn + c] = a4;
    xw[rbase + 5 * Dn + c] = a5;
    xw[rbase + 6 * Dn + c] = a6;
    xw[rbase + 7 * Dn + c] = a7;

    // ---- ah1/ah2 for the 8 rows of this block ----
    __shared__ float red[2][2][8];                    // [which][wave][row]
    float w1c = w1[c], w2c = w2[c];
    #pragma unroll
    for (int r = 0; r < 8; ++r) {
        float xv = x0[r * Dn + c];
        float p1 = xv * w1c, p2 = xv * w2c;
        #pragma unroll
        for (int o = 32; o > 0; o >>= 1) {
            p1 += __shfl_xor(p1, o);
            p2 += __shfl_xor(p2, o);
        }
        if (lane == 0) { red[0][wv][r] = p1; red[1][wv][r] = p2; }
    }
    __syncthreads();
    if (c < 8) {
        ah1[blockIdx.x * 8 + c] = red[0][0][c] + red[0][1][c] + b1[0];
        ah2[blockIdx.x * 8 + c] = red[1][0][c] + red[1][1][c] + b2[0];
    }
}

// ---------------------------------------------------------------------------
// Fused: masked softmax over neighbor list + sparse aggregate of xw + residual
// + ELU, updating x in place (row-private). Block = 128 threads (thread = d).
// blockIdx swizzle: slot = blockIdx&7 so each XCD's L2 tends to hold one
// slot's 1MB xw table.
__global__ void attn_agg(float* __restrict__ x, const float* __restrict__ xw,
                         const int* __restrict__ adj, const int* __restrict__ deg,
                         const float* __restrict__ ah1, const float* __restrict__ ah2) {
    int s = blockIdx.x & 7;
    int i = blockIdx.x >> 3;
    int r = s * Nn + i;
    int tid = threadIdx.x;

    __shared__ float p[MAXDEG];
    __shared__ int   nb[MAXDEG];
    __shared__ float zsh;

    int d = deg[r]; if (d > MAXDEG) d = MAXDEG;

    if (tid < 64 && d > 0) {
        float a1 = ah1[r];
        const int* al = adj + (size_t)r * MAXDEG;
        const float* ah2s = ah2 + (size_t)s * Nn;
        float v[2];
        float m = -INFINITY;
        #pragma unroll
        for (int t = 0; t < 2; ++t) {
            int k = tid + t * 64;
            if (k < d) {
                int j = al[k];
                nb[k] = j;
                float e = a1 + ah2s[j];
                e = e > 0.f ? e : 0.2f * e;   // leaky_relu(0.2)
                v[t] = e;
                m = fmaxf(m, e);
            } else v[t] = -INFINITY;
        }
        #pragma unroll
        for (int o = 32; o > 0; o >>= 1) m = fmaxf(m, __shfl_xor(m, o));
        float sum = 0.f;
        #pragma unroll
        for (int t = 0; t < 2; ++t) {
            int k = tid + t * 64;
            if (k < d) {
                float ex = __expf(v[t] - m);
                p[k] = ex;
                sum += ex;
            }
        }
        #pragma unroll
        for (int o = 32; o > 0; o >>= 1) sum += __shfl_xor(sum, o);
        if (tid == 0) zsh = sum;
    }
    __syncthreads();

    const float* xwS = xw + (size_t)s * Nn * Dn;
    float acc = 0.f;
    int k = 0;
    for (; k + 3 < d; k += 4) {
        float p0 = p[k], p1 = p[k+1], p2 = p[k+2], p3 = p[k+3];
        int j0 = nb[k], j1 = nb[k+1], j2 = nb[k+2], j3 = nb[k+3];
        acc += p0 * xwS[(size_t)j0 * Dn + tid];
        acc += p1 * xwS[(size_t)j1 * Dn + tid];
        acc += p2 * xwS[(size_t)j2 * Dn + tid];
        acc += p3 * xwS[(size_t)j3 * Dn + tid];
    }
    for (; k < d; ++k) acc += p[k] * xwS[(size_t)nb[k] * Dn + tid];

    size_t xi = (size_t)r * Dn + tid;
    float v0 = x[xi];
    float res;
    if (d > 0) {
        float t = v0 + acc / zsh;
        res = t > 0.f ? t : (expf(t) - 1.f);   // elu
    } else {
        res = v0 > 0.f ? v0 : (expf(v0) - 1.f);
    }
    x[xi] = res;
}

// ---------------------------------------------------------------------------
// Stage-1 reduction over rows: 32 chunks of 64 rows per batch, fwd+rev fused.
__global__ void reduce_partial(const float* __restrict__ x, float* __restrict__ part) {
    int b = blockIdx.x >> 5;
    int c = blockIdx.x & 31;
    int tid = threadIdx.x;                     // 0..127 = d
    const float* xf = x + ((size_t)(b * Nn) + c * 64) * Dn;
    const float* xr = x + ((size_t)((4 + b) * Nn) + c * 64) * Dn;
    float sv = 0.f;
    for (int i = 0; i < 64; ++i)
        sv += xf[(size_t)i * Dn + tid] + xr[(size_t)i * Dn + tid];
    part[(size_t)blockIdx.x * Dn + tid] = sv;
}

// ---------------------------------------------------------------------------
// Stage-2: mid[b] = sum of partials; out[b] = mid @ Wout + bout
__global__ void final_out(const float* __restrict__ part,
                          const float* __restrict__ Wout, const float* __restrict__ bout,
                          float* __restrict__ out) {
    int b = blockIdx.x;
    int tid = threadIdx.x;                     // 128 threads
    __shared__ float mid[Dn];
    float sv = 0.f;
    for (int c = 0; c < 32; ++c) sv += part[(size_t)(b * 32 + c) * Dn + tid];
    mid[tid] = sv;
    __syncthreads();
    if (tid < OUTn) {
        float o = bout[tid];
        #pragma unroll 4
        for (int k = 0; k < Dn; ++k) o = fmaf(mid[k], Wout[k * OUTn + tid], o);
        out[b * OUTn + tid] = o;
    }
}

// ---------------------------------------------------------------------------
extern "C" void kernel_launch(void* const* d_in, const int* in_sizes, int n_in,
                              void* d_out, int out_size, void* d_ws, size_t ws_size,
                              hipStream_t stream) {
    const float* INPUT = (const float*)d_in[0];
    const float* CFG   = (const float*)d_in[1];
    // d_in[2] = LFG, unused by the forward pass
    const float* w1    = (const float*)d_in[3];
    const float* b1    = (const float*)d_in[4];
    const float* w2    = (const float*)d_in[5];
    const float* b2    = (const float*)d_in[6];
    const float* Wm    = (const float*)d_in[7];
    const float* Wout  = (const float*)d_in[8];
    const float* bout  = (const float*)d_in[9];
    float* out = (float*)d_out;

    // workspace layout (~26.4 MB)
    float* x   = (float*)d_ws;                          // Sn*Nn*Dn   (8 MB)
    float* xw  = x + (size_t)Sn * Nn * Dn;              // Sn*Nn*Dn   (8 MB)
    int*   adj = (int*)(xw + (size_t)Sn * Nn * Dn);     // Sn*Nn*MAXDEG (8 MB)
    int*   deg = adj + (size_t)Sn * Nn * MAXDEG;        // Sn*Nn      (64 KB)
    float* ah1 = (float*)(deg + Sn * Nn);               // Sn*Nn      (64 KB)
    float* ah2 = ah1 + Sn * Nn;                         // Sn*Nn      (64 KB)
    float* part = ah2 + Sn * Nn;                        // Bn*32*Dn   (64 KB)
    unsigned long long* bits = (unsigned long long*)(part + Bn * 32 * Dn); // 2 MB

    fwd_and_bits<<<(Bn * Nn) / 4, 256, 0, stream>>>((const float4*)CFG, bits, adj, deg);
    rev_adj     <<<(Bn * Nn) / 4, 256, 0, stream>>>(bits, adj, deg);
    init_x      <<<(Bn * Nn * Dn) / 256, 256, 0, stream>>>(INPUT, x);

    for (int it = 0; it < NITER; ++it) {
        gemm_xw_ah<<<(Sn * Nn) / 8, 128, 0, stream>>>(x, Wm, xw, w1, b1, w2, b2, ah1, ah2);
        attn_agg  <<<Sn * Nn, 128, 0, stream>>>(x, xw, adj, deg, ah1, ah2);
    }

    reduce_partial<<<Bn * 32, 128, 0, stream>>>(x, part);
    final_out     <<<Bn, 128, 0, stream>>>(part, Wout, bout, out);
}

// Round 4
// 211.971 us; speedup vs baseline: 1.4836x; 1.0891x over previous
//
#include <hip/hip_runtime.h>
#include <cstdint>
#include <cstddef>

// Problem constants (match reference)
#define Bn 4
#define Nn 2048
#define Dn 128
#define OUTn 64
#define Sn 8          // 4 batches x {fwd, rev}
#define MAXDEG 128    // binomial(2048, 1/32): mean 64, sd 7.9; max over 16K rows ~99
#define NITER 3

// ---------------------------------------------------------------------------
// deposit low 16 bits of x at bit positions 0,4,8,...,60
__device__ __forceinline__ unsigned long long spread4(unsigned long long x) {
    x &= 0xFFFFull;
    x = (x | (x << 24)) & 0x000000FF000000FFull;
    x = (x | (x << 12)) & 0x000F000F000F000Full;
    x = (x | (x << 6))  & 0x0303030303030303ull;
    x = (x | (x << 3))  & 0x1111111111111111ull;
    return x;
}

// ---------------------------------------------------------------------------
// One wave per forward row (b,i). float4 loads (16B/lane => 256 cols/iter).
// Produces: forward adjacency (sorted, deterministic), degree, and a bitmask
// of CFG stored word-COLUMN-major: bits[b][jw][i] (jw = j/64, i = row).
__global__ void fwd_and_bits(const float4* __restrict__ cfg4,
                             unsigned long long* __restrict__ bits,
                             int* __restrict__ adj, int* __restrict__ deg) {
    int row  = blockIdx.x * 4 + (threadIdx.x >> 6);   // [0, Bn*Nn)
    int lane = threadIdx.x & 63;
    int b = row >> 11;
    int i = row & (Nn - 1);
    const float4* crow = cfg4 + (size_t)row * (Nn / 4);
    int* dst = adj + (size_t)row * MAXDEG;
    int cnt = 0;
    for (int j0 = 0; j0 < Nn; j0 += 256) {
        float4 v = crow[(j0 >> 2) + lane];
        int nib = (v.x != 0.f) | ((v.y != 0.f) << 1) |
                  ((v.z != 0.f) << 2) | ((v.w != 0.f) << 3);
        unsigned long long m0 = __ballot(nib & 1);
        unsigned long long m1 = __ballot(nib & 2);
        unsigned long long m2 = __ballot(nib & 4);
        unsigned long long m3 = __ballot(nib & 8);
        // exclusive prefix (ascending-column order) for this lane
        unsigned long long below = (1ull << lane) - 1ull;  // lane 63: low 63 bits
        int off = __popcll(m0 & below) + __popcll(m1 & below) +
                  __popcll(m2 & below) + __popcll(m3 & below);
        int total = __popcll(m0) + __popcll(m1) + __popcll(m2) + __popcll(m3);
        int base = cnt + off;
        int col = j0 + 4 * lane;
        if (nib & 1) { if (base < MAXDEG) dst[base] = col;     base++; }
        if (nib & 2) { if (base < MAXDEG) dst[base] = col + 1; base++; }
        if (nib & 4) { if (base < MAXDEG) dst[base] = col + 2; base++; }
        if (nib & 8) { if (base < MAXDEG) dst[base] = col + 3; base++; }
        // assemble the 4 bitmask words (cols j0+64w .. j0+64w+63), lanes 0..3
        if (lane < 4) {
            int sh = lane << 4;
            unsigned long long w = spread4(m0 >> sh) | (spread4(m1 >> sh) << 1) |
                                   (spread4(m2 >> sh) << 2) | (spread4(m3 >> sh) << 3);
            int jw = (j0 >> 6) + lane;
            bits[((size_t)(b * 32 + jw)) * Nn + i] = w;
        }
        cnt += total;
    }
    if (lane == 0) deg[row] = (cnt < MAXDEG ? cnt : MAXDEG);
}

// ---------------------------------------------------------------------------
// One wave per reverse row (b,j): read plane bits[b][j>>6][*] contiguously;
// the 16KB plane is shared by 64 consecutive rows (L1-resident). Ballot-
// compact ascending i. Deterministic and sorted — no atomics, no sort.
__global__ void rev_adj(const unsigned long long* __restrict__ bits,
                        int* __restrict__ adj, int* __restrict__ deg) {
    int r    = blockIdx.x * 4 + (threadIdx.x >> 6);   // [0, Bn*Nn)
    int lane = threadIdx.x & 63;
    int b = r >> 11;
    int j = r & (Nn - 1);
    const unsigned long long* col = bits + ((size_t)(b * 32 + (j >> 6))) * Nn;
    int bit = j & 63;
    int out_r = (Bn + b) * Nn + j;
    int* dst = adj + (size_t)out_r * MAXDEG;
    int cnt = 0;
    for (int i0 = 0; i0 < Nn; i0 += 64) {
        unsigned long long word = col[i0 + lane];
        bool e = (word >> bit) & 1;
        unsigned long long m = __ballot(e);
        if (e) {
            int pos = cnt + __popcll(m & ((1ull << lane) - 1ull));
            if (pos < MAXDEG) dst[pos] = i0 + lane;
        }
        cnt += __popcll(m);
    }
    if (lane == 0) deg[out_r] = (cnt < MAXDEG ? cnt : MAXDEG);
}

// ---------------------------------------------------------------------------
// x[s] = relu(INPUT[b]) for s = b and s = b+4
__global__ void init_x(const float* __restrict__ in, float* __restrict__ x) {
    int t = blockIdx.x * blockDim.x + threadIdx.x;    // [0, Bn*Nn*Dn)
    float v = in[t];
    v = v > 0.0f ? v : 0.0f;
    x[t] = v;
    x[(size_t)Bn * Nn * Dn + t] = v;
}

// ---------------------------------------------------------------------------
// Fused: xw = x @ W (8 rows per 128-thread block; x-row loads wave-uniform ->
// scalar path, W loads coalesced + cache resident) AND per-row attention
// scalars ah1/ah2 (shfl reduction over the feature dim).
__global__ void gemm_xw_ah(const float* __restrict__ x, const float* __restrict__ W,
                           float* __restrict__ xw,
                           const float* __restrict__ w1, const float* __restrict__ b1,
                           const float* __restrict__ w2, const float* __restrict__ b2,
                           float* __restrict__ ah1, float* __restrict__ ah2) {
    int c = threadIdx.x;                              // column 0..127
    int wv = c >> 6, lane = c & 63;
    size_t rbase = (size_t)blockIdx.x * 8 * Dn;
    const float* x0 = x + rbase;
    float a0 = 0.f, a1 = 0.f, a2 = 0.f, a3 = 0.f;
    float a4 = 0.f, a5 = 0.f, a6 = 0.f, a7 = 0.f;
    #pragma unroll 4
    for (int k = 0; k < Dn; ++k) {
        float w = W[k * Dn + c];
        a0 = fmaf(x0[0 * Dn + k], w, a0);
        a1 = fmaf(x0[1 * Dn + k], w, a1);
        a2 = fmaf(x0[2 * Dn + k], w, a2);
        a3 = fmaf(x0[3 * Dn + k], w, a3);
        a4 = fmaf(x0[4 * Dn + k], w, a4);
        a5 = fmaf(x0[5 * Dn + k], w, a5);
        a6 = fmaf(x0[6 * Dn + k], w, a6);
        a7 = fmaf(x0[7 * Dn + k], w, a7);
    }
    xw[rbase + 0 * Dn + c] = a0;
    xw[rbase + 1 * Dn + c] = a1;
    xw[rbase + 2 * Dn + c] = a2;
    xw[rbase + 3 * Dn + c] = a3;
    xw[rbase + 4 * Dn + c] = a4;
    xw[rbase + 5 * Dn + c] = a5;
    xw[rbase + 6 * Dn + c] = a6;
    xw[rbase + 7 * Dn + c] = a7;

    // ---- ah1/ah2 for the 8 rows of this block ----
    __shared__ float red[2][2][8];                    // [which][wave][row]
    float w1c = w1[c], w2c = w2[c];
    #pragma unroll
    for (int r = 0; r < 8; ++r) {
        float xv = x0[r * Dn + c];
        float p1 = xv * w1c, p2 = xv * w2c;
        #pragma unroll
        for (int o = 32; o > 0; o >>= 1) {
            p1 += __shfl_xor(p1, o);
            p2 += __shfl_xor(p2, o);
        }
        if (lane == 0) { red[0][wv][r] = p1; red[1][wv][r] = p2; }
    }
    __syncthreads();
    if (c < 8) {
        ah1[blockIdx.x * 8 + c] = red[0][0][c] + red[0][1][c] + b1[0];
        ah2[blockIdx.x * 8 + c] = red[1][0][c] + red[1][1][c] + b2[0];
    }
}

// ---------------------------------------------------------------------------
// Fused: masked softmax over neighbor list + sparse aggregate of xw + residual
// + ELU, updating x in place (row-private). Block = 128 threads.
// Gather phase: thread t owns feature-quad f=t&31 and neighbor-subgroup
// g=t>>5; 32 contiguous lanes cover one neighbor's 512B row (coalesced
// float4), 2 neighbors per wave-instruction, 4 FMAs per load.
// blockIdx swizzle: slot = blockIdx&7 -> each XCD's L2 holds one slot's xw.
__global__ void attn_agg(float* __restrict__ x, const float* __restrict__ xw,
                         const int* __restrict__ adj, const int* __restrict__ deg,
                         const float* __restrict__ ah1, const float* __restrict__ ah2) {
    int s = blockIdx.x & 7;
    int i = blockIdx.x >> 3;
    int r = s * Nn + i;
    int tid = threadIdx.x;

    __shared__ float2 pn[MAXDEG];    // .x = exp(e-m), .y = neighbor idx (bits)
    __shared__ float4 xacc[32];      // cross-wave reduction buffer
    __shared__ float zsh;

    int d = deg[r]; if (d > MAXDEG) d = MAXDEG;

    // ---- softmax over neighbor list (wave 0 only) ----
    if (tid < 64 && d > 0) {
        float a1 = ah1[r];
        const int* al = adj + (size_t)r * MAXDEG;
        const float* ah2s = ah2 + (size_t)s * Nn;
        float v[2];
        int   jj[2];
        float m = -INFINITY;
        #pragma unroll
        for (int t = 0; t < 2; ++t) {
            int k = tid + t * 64;
            if (k < d) {
                int j = al[k];
                jj[t] = j;
                float e = a1 + ah2s[j];
                e = e > 0.f ? e : 0.2f * e;   // leaky_relu(0.2)
                v[t] = e;
                m = fmaxf(m, e);
            } else v[t] = -INFINITY;
        }
        #pragma unroll
        for (int o = 32; o > 0; o >>= 1) m = fmaxf(m, __shfl_xor(m, o));
        float sum = 0.f;
        #pragma unroll
        for (int t = 0; t < 2; ++t) {
            int k = tid + t * 64;
            if (k < d) {
                float ex = __expf(v[t] - m);
                pn[k] = make_float2(ex, __int_as_float(jj[t]));
                sum += ex;
            }
        }
        #pragma unroll
        for (int o = 32; o > 0; o >>= 1) sum += __shfl_xor(sum, o);
        if (tid == 0) zsh = sum;
    }
    __syncthreads();

    // ---- sparse aggregate: acc[f] = sum_k p[k] * xw[nb[k]][4f..4f+3] ----
    const float4* xw4 = (const float4*)(xw + (size_t)s * Nn * Dn);
    int g = tid >> 5;                 // neighbor subgroup 0..3
    int f = tid & 31;                 // feature quad
    float4 acc = make_float4(0.f, 0.f, 0.f, 0.f);
    #pragma unroll 2
    for (int k = g; k < d; k += 4) {
        float2 q = pn[k];
        int j = __float_as_int(q.y);
        float4 v = xw4[(size_t)j * 32 + f];
        acc.x = fmaf(q.x, v.x, acc.x);
        acc.y = fmaf(q.x, v.y, acc.y);
        acc.z = fmaf(q.x, v.z, acc.z);
        acc.w = fmaf(q.x, v.w, acc.w);
    }
    // fold subgroup pairs within each wave (g0+g1 in wave0, g2+g3 in wave1)
    acc.x += __shfl_xor(acc.x, 32);
    acc.y += __shfl_xor(acc.y, 32);
    acc.z += __shfl_xor(acc.z, 32);
    acc.w += __shfl_xor(acc.w, 32);
    if (tid >= 64 && tid < 96) xacc[f] = acc;
    __syncthreads();

    // ---- residual + ELU + store (lanes 0..31) ----
    if (tid < 32) {
        float4 o = xacc[tid];
        acc.x += o.x; acc.y += o.y; acc.z += o.z; acc.w += o.w;
        float inv;
        if (d > 0) inv = 1.0f / zsh; else inv = 0.f;
        float4* x4 = (float4*)(x + (size_t)r * Dn);
        float4 v0 = x4[tid];
        float4 t, res;
        t.x = v0.x + acc.x * inv;
        t.y = v0.y + acc.y * inv;
        t.z = v0.z + acc.z * inv;
        t.w = v0.w + acc.w * inv;
        res.x = t.x > 0.f ? t.x : (expf(t.x) - 1.f);
        res.y = t.y > 0.f ? t.y : (expf(t.y) - 1.f);
        res.z = t.z > 0.f ? t.z : (expf(t.z) - 1.f);
        res.w = t.w > 0.f ? t.w : (expf(t.w) - 1.f);
        x4[tid] = res;
    }
}

// ---------------------------------------------------------------------------
// Stage-1 reduction over rows: 32 chunks of 64 rows per batch, fwd+rev fused.
__global__ void reduce_partial(const float* __restrict__ x, float* __restrict__ part) {
    int b = blockIdx.x >> 5;
    int c = blockIdx.x & 31;
    int tid = threadIdx.x;                     // 0..127 = d
    const float* xf = x + ((size_t)(b * Nn) + c * 64) * Dn;
    const float* xr = x + ((size_t)((4 + b) * Nn) + c * 64) * Dn;
    float sv = 0.f;
    for (int i = 0; i < 64; ++i)
        sv += xf[(size_t)i * Dn + tid] + xr[(size_t)i * Dn + tid];
    part[(size_t)blockIdx.x * Dn + tid] = sv;
}

// ---------------------------------------------------------------------------
// Stage-2: mid[b] = sum of partials; out[b] = mid @ Wout + bout
__global__ void final_out(const float* __restrict__ part,
                          const float* __restrict__ Wout, const float* __restrict__ bout,
                          float* __restrict__ out) {
    int b = blockIdx.x;
    int tid = threadIdx.x;                     // 128 threads
    __shared__ float mid[Dn];
    float sv = 0.f;
    for (int c = 0; c < 32; ++c) sv += part[(size_t)(b * 32 + c) * Dn + tid];
    mid[tid] = sv;
    __syncthreads();
    if (tid < OUTn) {
        float o = bout[tid];
        #pragma unroll 4
        for (int k = 0; k < Dn; ++k) o = fmaf(mid[k], Wout[k * OUTn + tid], o);
        out[b * OUTn + tid] = o;
    }
}

// ---------------------------------------------------------------------------
extern "C" void kernel_launch(void* const* d_in, const int* in_sizes, int n_in,
                              void* d_out, int out_size, void* d_ws, size_t ws_size,
                              hipStream_t stream) {
    const float* INPUT = (const float*)d_in[0];
    const float* CFG   = (const float*)d_in[1];
    // d_in[2] = LFG, unused by the forward pass
    const float* w1    = (const float*)d_in[3];
    const float* b1    = (const float*)d_in[4];
    const float* w2    = (const float*)d_in[5];
    const float* b2    = (const float*)d_in[6];
    const float* Wm    = (const float*)d_in[7];
    const float* Wout  = (const float*)d_in[8];
    const float* bout  = (const float*)d_in[9];
    float* out = (float*)d_out;

    // workspace layout (~26.4 MB)
    float* x   = (float*)d_ws;                          // Sn*Nn*Dn   (8 MB)
    float* xw  = x + (size_t)Sn * Nn * Dn;              // Sn*Nn*Dn   (8 MB)
    int*   adj = (int*)(xw + (size_t)Sn * Nn * Dn);     // Sn*Nn*MAXDEG (8 MB)
    int*   deg = adj + (size_t)Sn * Nn * MAXDEG;        // Sn*Nn      (64 KB)
    float* ah1 = (float*)(deg + Sn * Nn);               // Sn*Nn      (64 KB)
    float* ah2 = ah1 + Sn * Nn;                         // Sn*Nn      (64 KB)
    float* part = ah2 + Sn * Nn;                        // Bn*32*Dn   (64 KB)
    unsigned long long* bits = (unsigned long long*)(part + Bn * 32 * Dn); // 2 MB

    fwd_and_bits<<<(Bn * Nn) / 4, 256, 0, stream>>>((const float4*)CFG, bits, adj, deg);
    rev_adj     <<<(Bn * Nn) / 4, 256, 0, stream>>>(bits, adj, deg);
    init_x      <<<(Bn * Nn * Dn) / 256, 256, 0, stream>>>(INPUT, x);

    for (int it = 0; it < NITER; ++it) {
        gemm_xw_ah<<<(Sn * Nn) / 8, 128, 0, stream>>>(x, Wm, xw, w1, b1, w2, b2, ah1, ah2);
        attn_agg  <<<Sn * Nn, 128, 0, stream>>>(x, xw, adj, deg, ah1, ah2);
    }

    reduce_partial<<<Bn * 32, 128, 0, stream>>>(x, part);
    final_out     <<<Bn, 128, 0, stream>>>(part, Wout, bout, out);
}

// Round 5
// 207.102 us; speedup vs baseline: 1.5185x; 1.0235x over previous
//
#include <hip/hip_runtime.h>
#include <hip/hip_fp16.h>
#include <cstdint>
#include <cstddef>

// Problem constants (match reference)
#define Bn 4
#define Nn 2048
#define Dn 128
#define OUTn 64
#define Sn 8          // 4 batches x {fwd, rev}
#define MAXDEG 128    // binomial(2048, 1/32): mean 64, sd 7.9; max over 16K rows ~99
#define NITER 3

// ---------------------------------------------------------------------------
// deposit low 16 bits of x at bit positions 0,4,8,...,60
__device__ __forceinline__ unsigned long long spread4(unsigned long long x) {
    x &= 0xFFFFull;
    x = (x | (x << 24)) & 0x000000FF000000FFull;
    x = (x | (x << 12)) & 0x000F000F000F000Full;
    x = (x | (x << 6))  & 0x0303030303030303ull;
    x = (x | (x << 3))  & 0x1111111111111111ull;
    return x;
}

// ---------------------------------------------------------------------------
// One wave per forward row (b,i). float4 loads (16B/lane => 256 cols/iter).
// Produces: forward adjacency (sorted, deterministic), degree, and a bitmask
// of CFG stored word-COLUMN-major: bits[b][jw][i] (jw = j/64, i = row).
__global__ void fwd_and_bits(const float4* __restrict__ cfg4,
                             unsigned long long* __restrict__ bits,
                             int* __restrict__ adj, int* __restrict__ deg) {
    int row  = blockIdx.x * 4 + (threadIdx.x >> 6);   // [0, Bn*Nn)
    int lane = threadIdx.x & 63;
    int b = row >> 11;
    int i = row & (Nn - 1);
    const float4* crow = cfg4 + (size_t)row * (Nn / 4);
    int* dst = adj + (size_t)row * MAXDEG;
    int cnt = 0;
    for (int j0 = 0; j0 < Nn; j0 += 256) {
        float4 v = crow[(j0 >> 2) + lane];
        int nib = (v.x != 0.f) | ((v.y != 0.f) << 1) |
                  ((v.z != 0.f) << 2) | ((v.w != 0.f) << 3);
        unsigned long long m0 = __ballot(nib & 1);
        unsigned long long m1 = __ballot(nib & 2);
        unsigned long long m2 = __ballot(nib & 4);
        unsigned long long m3 = __ballot(nib & 8);
        // exclusive prefix (ascending-column order) for this lane
        unsigned long long below = (1ull << lane) - 1ull;  // lane 63: low 63 bits
        int off = __popcll(m0 & below) + __popcll(m1 & below) +
                  __popcll(m2 & below) + __popcll(m3 & below);
        int total = __popcll(m0) + __popcll(m1) + __popcll(m2) + __popcll(m3);
        int base = cnt + off;
        int col = j0 + 4 * lane;
        if (nib & 1) { if (base < MAXDEG) dst[base] = col;     base++; }
        if (nib & 2) { if (base < MAXDEG) dst[base] = col + 1; base++; }
        if (nib & 4) { if (base < MAXDEG) dst[base] = col + 2; base++; }
        if (nib & 8) { if (base < MAXDEG) dst[base] = col + 3; base++; }
        // assemble the 4 bitmask words (cols j0+64w .. j0+64w+63), lanes 0..3
        if (lane < 4) {
            int sh = lane << 4;
            unsigned long long w = spread4(m0 >> sh) | (spread4(m1 >> sh) << 1) |
                                   (spread4(m2 >> sh) << 2) | (spread4(m3 >> sh) << 3);
            int jw = (j0 >> 6) + lane;
            bits[((size_t)(b * 32 + jw)) * Nn + i] = w;
        }
        cnt += total;
    }
    if (lane == 0) deg[row] = (cnt < MAXDEG ? cnt : MAXDEG);
}

// ---------------------------------------------------------------------------
// One wave per reverse row (b,j): read plane bits[b][j>>6][*] contiguously;
// the 16KB plane is shared by 64 consecutive rows (L1-resident). Ballot-
// compact ascending i. Deterministic and sorted — no atomics, no sort.
__global__ void rev_adj(const unsigned long long* __restrict__ bits,
                        int* __restrict__ adj, int* __restrict__ deg) {
    int r    = blockIdx.x * 4 + (threadIdx.x >> 6);   // [0, Bn*Nn)
    int lane = threadIdx.x & 63;
    int b = r >> 11;
    int j = r & (Nn - 1);
    const unsigned long long* col = bits + ((size_t)(b * 32 + (j >> 6))) * Nn;
    int bit = j & 63;
    int out_r = (Bn + b) * Nn + j;
    int* dst = adj + (size_t)out_r * MAXDEG;
    int cnt = 0;
    for (int i0 = 0; i0 < Nn; i0 += 64) {
        unsigned long long word = col[i0 + lane];
        bool e = (word >> bit) & 1;
        unsigned long long m = __ballot(e);
        if (e) {
            int pos = cnt + __popcll(m & ((1ull << lane) - 1ull));
            if (pos < MAXDEG) dst[pos] = i0 + lane;
        }
        cnt += __popcll(m);
    }
    if (lane == 0) deg[out_r] = (cnt < MAXDEG ? cnt : MAXDEG);
}

// ---------------------------------------------------------------------------
// x[s] = relu(INPUT[b]) for s = b and s = b+4
__global__ void init_x(const float* __restrict__ in, float* __restrict__ x) {
    int t = blockIdx.x * blockDim.x + threadIdx.x;    // [0, Bn*Nn*Dn)
    float v = in[t];
    v = v > 0.0f ? v : 0.0f;
    x[t] = v;
    x[(size_t)Bn * Nn * Dn + t] = v;
}

// ---------------------------------------------------------------------------
// Fused: xw = fp16(x @ W) (8 rows per 128-thread block; x-row loads wave-
// uniform -> scalar path, W loads coalesced + cache resident) AND per-row
// attention scalars ah1/ah2 (shfl reduction over the feature dim).
__global__ void gemm_xw_ah(const float* __restrict__ x, const float* __restrict__ W,
                           __half* __restrict__ xwh,
                           const float* __restrict__ w1, const float* __restrict__ b1,
                           const float* __restrict__ w2, const float* __restrict__ b2,
                           float* __restrict__ ah1, float* __restrict__ ah2) {
    int c = threadIdx.x;                              // column 0..127
    int wv = c >> 6, lane = c & 63;
    size_t rbase = (size_t)blockIdx.x * 8 * Dn;
    const float* x0 = x + rbase;
    float a0 = 0.f, a1 = 0.f, a2 = 0.f, a3 = 0.f;
    float a4 = 0.f, a5 = 0.f, a6 = 0.f, a7 = 0.f;
    #pragma unroll 4
    for (int k = 0; k < Dn; ++k) {
        float w = W[k * Dn + c];
        a0 = fmaf(x0[0 * Dn + k], w, a0);
        a1 = fmaf(x0[1 * Dn + k], w, a1);
        a2 = fmaf(x0[2 * Dn + k], w, a2);
        a3 = fmaf(x0[3 * Dn + k], w, a3);
        a4 = fmaf(x0[4 * Dn + k], w, a4);
        a5 = fmaf(x0[5 * Dn + k], w, a5);
        a6 = fmaf(x0[6 * Dn + k], w, a6);
        a7 = fmaf(x0[7 * Dn + k], w, a7);
    }
    xwh[rbase + 0 * Dn + c] = __float2half(a0);
    xwh[rbase + 1 * Dn + c] = __float2half(a1);
    xwh[rbase + 2 * Dn + c] = __float2half(a2);
    xwh[rbase + 3 * Dn + c] = __float2half(a3);
    xwh[rbase + 4 * Dn + c] = __float2half(a4);
    xwh[rbase + 5 * Dn + c] = __float2half(a5);
    xwh[rbase + 6 * Dn + c] = __float2half(a6);
    xwh[rbase + 7 * Dn + c] = __float2half(a7);

    // ---- ah1/ah2 for the 8 rows of this block ----
    __shared__ float red[2][2][8];                    // [which][wave][row]
    float w1c = w1[c], w2c = w2[c];
    #pragma unroll
    for (int r = 0; r < 8; ++r) {
        float xv = x0[r * Dn + c];
        float p1 = xv * w1c, p2 = xv * w2c;
        #pragma unroll
        for (int o = 32; o > 0; o >>= 1) {
            p1 += __shfl_xor(p1, o);
            p2 += __shfl_xor(p2, o);
        }
        if (lane == 0) { red[0][wv][r] = p1; red[1][wv][r] = p2; }
    }
    __syncthreads();
    if (c < 8) {
        ah1[blockIdx.x * 8 + c] = red[0][0][c] + red[0][1][c] + b1[0];
        ah2[blockIdx.x * 8 + c] = red[1][0][c] + red[1][1][c] + b2[0];
    }
}

// ---------------------------------------------------------------------------
// Fused: masked softmax over neighbor list + sparse aggregate of fp16 xw +
// residual + ELU, updating x in place (row-private). Block = 128 threads.
// Gather: 16 lanes cover one neighbor's 256B fp16 row (uint4 = 8 features per
// lane), 8 neighbor-subgroups per block -> 4 neighbors per wave-instruction.
// blockIdx swizzle: slot = blockIdx&7 -> each XCD's L2 holds one slot's xw.
__global__ void attn_agg(float* __restrict__ x, const __half* __restrict__ xwh,
                         const int* __restrict__ adj, const int* __restrict__ deg,
                         const float* __restrict__ ah1, const float* __restrict__ ah2) {
    int s = blockIdx.x & 7;
    int i = blockIdx.x >> 3;
    int r = s * Nn + i;
    int tid = threadIdx.x;

    __shared__ float2 pn[MAXDEG];    // .x = exp(e-m), .y = neighbor idx (bits)
    __shared__ float4 xaccA[16];     // cross-wave reduction buffers
    __shared__ float4 xaccB[16];
    __shared__ float zsh;

    int d = deg[r]; if (d > MAXDEG) d = MAXDEG;

    // ---- softmax over neighbor list (wave 0 only) ----
    if (tid < 64 && d > 0) {
        float a1 = ah1[r];
        const int* al = adj + (size_t)r * MAXDEG;
        const float* ah2s = ah2 + (size_t)s * Nn;
        float v[2];
        int   jj[2];
        float m = -INFINITY;
        #pragma unroll
        for (int t = 0; t < 2; ++t) {
            int k = tid + t * 64;
            if (k < d) {
                int j = al[k];
                jj[t] = j;
                float e = a1 + ah2s[j];
                e = e > 0.f ? e : 0.2f * e;   // leaky_relu(0.2)
                v[t] = e;
                m = fmaxf(m, e);
            } else v[t] = -INFINITY;
        }
        #pragma unroll
        for (int o = 32; o > 0; o >>= 1) m = fmaxf(m, __shfl_xor(m, o));
        float sum = 0.f;
        #pragma unroll
        for (int t = 0; t < 2; ++t) {
            int k = tid + t * 64;
            if (k < d) {
                float ex = __expf(v[t] - m);
                pn[k] = make_float2(ex, __int_as_float(jj[t]));
                sum += ex;
            }
        }
        #pragma unroll
        for (int o = 32; o > 0; o >>= 1) sum += __shfl_xor(sum, o);
        if (tid == 0) zsh = sum;
    }
    __syncthreads();

    // ---- sparse aggregate: 8 subgroups x 16 lanes; lane f owns features
    //      8f..8f+7 of its subgroup's neighbors ----
    const uint4* xwu = (const uint4*)(xwh + (size_t)s * Nn * Dn);  // 16 uint4/row
    int g = tid >> 4;                 // neighbor subgroup 0..7
    int f = tid & 15;                 // feature octet
    float4 accA = make_float4(0.f, 0.f, 0.f, 0.f);
    float4 accB = make_float4(0.f, 0.f, 0.f, 0.f);
    for (int k = g; k < d; k += 8) {
        float2 q = pn[k];
        int j = __float_as_int(q.y);
        uint4 v = xwu[(size_t)j * 16 + f];
        const __half2* hh = (const __half2*)&v;
        float2 t0 = __half22float2(hh[0]);
        float2 t1 = __half22float2(hh[1]);
        float2 t2 = __half22float2(hh[2]);
        float2 t3 = __half22float2(hh[3]);
        accA.x = fmaf(q.x, t0.x, accA.x);
        accA.y = fmaf(q.x, t0.y, accA.y);
        accA.z = fmaf(q.x, t1.x, accA.z);
        accA.w = fmaf(q.x, t1.y, accA.w);
        accB.x = fmaf(q.x, t2.x, accB.x);
        accB.y = fmaf(q.x, t2.y, accB.y);
        accB.z = fmaf(q.x, t3.x, accB.z);
        accB.w = fmaf(q.x, t3.y, accB.w);
    }
    // fold the 4 subgroups within each wave (every lane ends with wave total)
    #pragma unroll
    for (int o = 16; o <= 32; o <<= 1) {
        accA.x += __shfl_xor(accA.x, o);
        accA.y += __shfl_xor(accA.y, o);
        accA.z += __shfl_xor(accA.z, o);
        accA.w += __shfl_xor(accA.w, o);
        accB.x += __shfl_xor(accB.x, o);
        accB.y += __shfl_xor(accB.y, o);
        accB.z += __shfl_xor(accB.z, o);
        accB.w += __shfl_xor(accB.w, o);
    }
    if (tid >= 64 && tid < 80) { xaccA[f] = accA; xaccB[f] = accB; }
    __syncthreads();

    // ---- residual + ELU + store (lanes 0..15, 8 features each) ----
    if (tid < 16) {
        float4 oA = xaccA[tid], oB = xaccB[tid];
        accA.x += oA.x; accA.y += oA.y; accA.z += oA.z; accA.w += oA.w;
        accB.x += oB.x; accB.y += oB.y; accB.z += oB.z; accB.w += oB.w;
        float inv = (d > 0) ? 1.0f / zsh : 0.f;
        float4* x4 = (float4*)(x + (size_t)r * Dn);
        float4 vA = x4[2 * tid], vB = x4[2 * tid + 1];
        float4 tA, tB, rA, rB;
        tA.x = vA.x + accA.x * inv;  tA.y = vA.y + accA.y * inv;
        tA.z = vA.z + accA.z * inv;  tA.w = vA.w + accA.w * inv;
        tB.x = vB.x + accB.x * inv;  tB.y = vB.y + accB.y * inv;
        tB.z = vB.z + accB.z * inv;  tB.w = vB.w + accB.w * inv;
        rA.x = tA.x > 0.f ? tA.x : (expf(tA.x) - 1.f);
        rA.y = tA.y > 0.f ? tA.y : (expf(tA.y) - 1.f);
        rA.z = tA.z > 0.f ? tA.z : (expf(tA.z) - 1.f);
        rA.w = tA.w > 0.f ? tA.w : (expf(tA.w) - 1.f);
        rB.x = tB.x > 0.f ? tB.x : (expf(tB.x) - 1.f);
        rB.y = tB.y > 0.f ? tB.y : (expf(tB.y) - 1.f);
        rB.z = tB.z > 0.f ? tB.z : (expf(tB.z) - 1.f);
        rB.w = tB.w > 0.f ? tB.w : (expf(tB.w) - 1.f);
        x4[2 * tid]     = rA;
        x4[2 * tid + 1] = rB;
    }
}

// ---------------------------------------------------------------------------
// Stage-1 reduction over rows: 32 chunks of 64 rows per batch, fwd+rev fused.
__global__ void reduce_partial(const float* __restrict__ x, float* __restrict__ part) {
    int b = blockIdx.x >> 5;
    int c = blockIdx.x & 31;
    int tid = threadIdx.x;                     // 0..127 = d
    const float* xf = x + ((size_t)(b * Nn) + c * 64) * Dn;
    const float* xr = x + ((size_t)((4 + b) * Nn) + c * 64) * Dn;
    float sv = 0.f;
    for (int i = 0; i < 64; ++i)
        sv += xf[(size_t)i * Dn + tid] + xr[(size_t)i * Dn + tid];
    part[(size_t)blockIdx.x * Dn + tid] = sv;
}

// ---------------------------------------------------------------------------
// Stage-2: mid[b] = sum of partials; out[b] = mid @ Wout + bout
__global__ void final_out(const float* __restrict__ part,
                          const float* __restrict__ Wout, const float* __restrict__ bout,
                          float* __restrict__ out) {
    int b = blockIdx.x;
    int tid = threadIdx.x;                     // 128 threads
    __shared__ float mid[Dn];
    float sv = 0.f;
    for (int c = 0; c < 32; ++c) sv += part[(size_t)(b * 32 + c) * Dn + tid];
    mid[tid] = sv;
    __syncthreads();
    if (tid < OUTn) {
        float o = bout[tid];
        #pragma unroll 4
        for (int k = 0; k < Dn; ++k) o = fmaf(mid[k], Wout[k * OUTn + tid], o);
        out[b * OUTn + tid] = o;
    }
}

// ---------------------------------------------------------------------------
extern "C" void kernel_launch(void* const* d_in, const int* in_sizes, int n_in,
                              void* d_out, int out_size, void* d_ws, size_t ws_size,
                              hipStream_t stream) {
    const float* INPUT = (const float*)d_in[0];
    const float* CFG   = (const float*)d_in[1];
    // d_in[2] = LFG, unused by the forward pass
    const float* w1    = (const float*)d_in[3];
    const float* b1    = (const float*)d_in[4];
    const float* w2    = (const float*)d_in[5];
    const float* b2    = (const float*)d_in[6];
    const float* Wm    = (const float*)d_in[7];
    const float* Wout  = (const float*)d_in[8];
    const float* bout  = (const float*)d_in[9];
    float* out = (float*)d_out;

    // workspace layout (~22.4 MB)
    float*  x   = (float*)d_ws;                          // Sn*Nn*Dn   (8 MB)
    __half* xwh = (__half*)(x + (size_t)Sn * Nn * Dn);   // Sn*Nn*Dn   (4 MB)
    int*    adj = (int*)(xwh + (size_t)Sn * Nn * Dn);    // Sn*Nn*MAXDEG (8 MB)
    int*    deg = adj + (size_t)Sn * Nn * MAXDEG;        // Sn*Nn      (64 KB)
    float*  ah1 = (float*)(deg + Sn * Nn);               // Sn*Nn      (64 KB)
    float*  ah2 = ah1 + Sn * Nn;                         // Sn*Nn      (64 KB)
    float*  part = ah2 + Sn * Nn;                        // Bn*32*Dn   (64 KB)
    unsigned long long* bits = (unsigned long long*)(part + Bn * 32 * Dn); // 2 MB

    fwd_and_bits<<<(Bn * Nn) / 4, 256, 0, stream>>>((const float4*)CFG, bits, adj, deg);
    rev_adj     <<<(Bn * Nn) / 4, 256, 0, stream>>>(bits, adj, deg);
    init_x      <<<(Bn * Nn * Dn) / 256, 256, 0, stream>>>(INPUT, x);

    for (int it = 0; it < NITER; ++it) {
        gemm_xw_ah<<<(Sn * Nn) / 8, 128, 0, stream>>>(x, Wm, xwh, w1, b1, w2, b2, ah1, ah2);
        attn_agg  <<<Sn * Nn, 128, 0, stream>>>(x, xwh, adj, deg, ah1, ah2);
    }

    reduce_partial<<<Bn * 32, 128, 0, stream>>>(x, part);
    final_out     <<<Bn, 128, 0, stream>>>(part, Wout, bout, out);
}